// Round 12
// baseline (300.984 us; speedup 1.0000x reference)
//
#include <hip/hip_runtime.h>
#include <hip/hip_bf16.h>

#define IN_F   4096
#define OUT_F  4096
#define PACKED (IN_F / 8)      // 512
#define M_DIM  8192            // 4 * 2048
#define N_DIM  4096
#define K_DIM  4096

#define BM 256
#define BN 256
#define BK 64
#define NT (K_DIM / BK)        // 64 K-tiles
#define NHALF (4 * NT)

typedef __bf16 bf16x8  __attribute__((ext_vector_type(8)));
typedef float  f32x16  __attribute__((ext_vector_type(16)));

#define BAR() asm volatile("s_barrier" ::: "memory")
#define VMCNT(n) asm volatile("s_waitcnt vmcnt(" #n ")" ::: "memory")
#define AS1 __attribute__((address_space(1)))
#define AS3 __attribute__((address_space(3)))

// ---------------------------------------------------------------------------
// Fragment-ordered DRAM layout, 32x32x16 variant:
//   [128-row-half][kTile64(64)][subtile st(16)][1024 B]
//   subtile st = rb*4 + ks: rows rb*32..+31 (in the half), k ks*16..+15
//   chunk l (=byte/16): row32 = l&31, k8 = (l>>5)*8  (A/B frag order for
//   mfma_32x32x16: lane=row&31 | (k>>3)<<5, 8 consecutive k per lane)
// A wave staging/reading a subtile touches a CONTIGUOUS 1 KB.
// ---------------------------------------------------------------------------

// Pre-pass 1: dequantize int4 -> bf16 fragment-ordered W.
__global__ __launch_bounds__(256) void dequant_kernel(
    const int* __restrict__ qw, const float* __restrict__ qs,
    const int* __restrict__ qz, __bf16* __restrict__ W)
{
    int ch = blockIdx.x * blockDim.x + threadIdx.x;
    if (ch >= OUT_F * PACKED) return;
    int l     = ch & 63;
    int st    = (ch >> 6) & 15;
    int kTile = (ch >> 10) & 63;
    int half  = ch >> 16;
    int rb = st >> 2, ks = st & 3;
    int o  = half * 128 + rb * 32 + (l & 31);
    int k0 = kTile * 64 + ks * 16 + ((l >> 5) << 3);
    int g  = k0 >> 7;
    unsigned int q = (unsigned int)qw[o * PACKED + (k0 >> 3)];
    float scale = qs[g * OUT_F + o];
    float zero  = (float)qz[g * OUT_F + o];
    bf16x8 v;
#pragma unroll
    for (int i = 0; i < 8; ++i) {
        float wi = (float)((q >> (4 * i)) & 15u);
        v[i] = (__bf16)((wi - zero) * scale);
    }
    *reinterpret_cast<bf16x8*>(&W[(size_t)ch * 8]) = v;
}

// Pre-pass 2: x f32 -> bf16 fragment-ordered xb.
__global__ __launch_bounds__(256) void cvt_kernel(
    const float* __restrict__ x, __bf16* __restrict__ xb, int nch)
{
    int ch = blockIdx.x * blockDim.x + threadIdx.x;
    if (ch >= nch) return;
    int l     = ch & 63;
    int st    = (ch >> 6) & 15;
    int kTile = (ch >> 10) & 63;
    int half  = ch >> 16;
    int rb = st >> 2, ks = st & 3;
    int m  = half * 128 + rb * 32 + (l & 31);
    int k0 = kTile * 64 + ks * 16 + ((l >> 5) << 3);
    const float4* xv = reinterpret_cast<const float4*>(x + (size_t)m * K_DIM + k0);
    float4 a = xv[0];
    float4 b = xv[1];
    bf16x8 v;
    v[0] = (__bf16)a.x; v[1] = (__bf16)a.y; v[2] = (__bf16)a.z; v[3] = (__bf16)a.w;
    v[4] = (__bf16)b.x; v[5] = (__bf16)b.y; v[6] = (__bf16)b.z; v[7] = (__bf16)b.w;
    reinterpret_cast<bf16x8*>(xb)[ch] = v;
}

// ---------------------------------------------------------------------------
// GEMM: r4's exact schedule, mfma_f32_32x32x16_bf16 geometry.
// 256x256 tile, BK=64, 8 waves (2Mx4N, 128x64 out/wave = 4x2 32x32 tiles).
//   p0: read A mb01 (8) + B nb0 (4); stage B1(t+1); Q0 = mb01*nb0 (8 MFMA)
//   p1: read A mb23 (8);             stage A0(t+2); Q1 = mb23*nb0
//   p2: read B nb1 (4, overwrite);   stage A1(t+2); Q2 = mb01*nb1
//   p3:                              stage B0(t+2); Q3 = mb23*nb1; VMCNT(6)
// ---------------------------------------------------------------------------
__global__ __launch_bounds__(512, 2) void gemm_kernel(
    const __bf16* __restrict__ A, const __bf16* __restrict__ B,
    float* __restrict__ C)
{
    extern __shared__ __bf16 lds[];   // 2 bufs x (A 16384 + B 16384) = 128 KiB

    const int tid  = threadIdx.x;
    const int lane = tid & 63;
    const int wave = tid >> 6;        // 0..7
    const int wm   = wave >> 2;       // 0..1  (128-row half of tile)
    const int wn   = wave & 3;        // 0..3  (64-col group)
    const int lane8 = lane * 8;

    // bijective XCD swizzle: 512 blocks = 8 XCDs x 64
    const int bid = blockIdx.x;
    const int swz = (bid & 7) * 64 + (bid >> 3);
    const int nBase = (swz & 15) * BN;
    const int mBase = (swz >> 4) * BM;
    const int mHalf0 = mBase >> 7;
    const int nHalf0 = nBase >> 7;

    // stage one 128x64 half-tile (16 subtiles): 2 contiguous-1KB loads/thread
    auto stage_half = [&](const __bf16* __restrict__ srcFrag, __bf16* dstMat,
                          int halfGlobal, int kTile, int hh) {
#pragma unroll
        for (int i = 0; i < 2; ++i) {
            const int st = i * 8 + wave;          // wave-uniform
            const __bf16* base = srcFrag + ((size_t)(halfGlobal * 64 + kTile) << 13);
            __builtin_amdgcn_global_load_lds(
                (const AS1 void*)(base + st * 512 + lane8),
                (AS3 void*)(dstMat + (hh * 16 + st) * 512 + lane8),
                16, 0, 0);
        }
    };
    // h: 0=A half0, 1=A half1, 2=B half0, 3=B half1  (into buffer of tile t)
    auto stage_H = [&](int H) {
        const int t = H >> 2;
        const int h = H & 3;
        __bf16* base = lds + (size_t)(t & 1) * 32768 + (size_t)(h >> 1) * 16384;
        if (h & 2) stage_half(B, base, nHalf0 + (h & 1), t, h & 1);
        else       stage_half(A, base, mHalf0 + (h & 1), t, h & 1);
    };

    f32x16 acc[4][2];
#pragma unroll
    for (int i = 0; i < 4; ++i)
#pragma unroll
        for (int j = 0; j < 2; ++j)
            acc[i][j] = (f32x16)0.0f;

    bf16x8 Af[4][4];   // [mb][ks]
    bf16x8 Bf[4];      // [ks] for current nb (overwritten at p2)

    // A frag (mb, ks): wave's 128-half is wm; subtile = mb*4+ks
#define LDA(lA, mb, ks) (*(const bf16x8*)((lA) + (size_t)wm * 8192 + (((mb) * 4 + (ks)) << 9) + lane8))
    // B frag (nb, ks): col-block cb = wn*2+nb in 0..7; half = cb>>2, rb = cb&3
#define LDB(lB, nb, ks) (*(const bf16x8*)((lB) + (size_t)(((wn * 2 + (nb)) >> 2)) * 8192 + ((((((wn * 2 + (nb)) & 3)) * 4 + (ks))) << 9) + lane8))

    // Prologue: tile0 all 4 halves + tile1 halves A0,A1,B0
#pragma unroll
    for (int H = 0; H < 7; ++H) stage_H(H);
    VMCNT(6);                          // tile0 complete, 3 half-tiles in flight
    BAR();

    for (int t = 0; t < NT; ++t) {
        const __bf16* lA = lds + (size_t)(t & 1) * 32768;
        const __bf16* lB = lA + 16384;
        const int Hb = 4 * t + 7;     // stage lead = +7 halves

        // p0: read A mb0-1 (8) + B nb0 (4); stage (t+1,B1); MFMA Q0
#pragma unroll
        for (int mb = 0; mb < 2; ++mb)
#pragma unroll
            for (int ks = 0; ks < 4; ++ks) Af[mb][ks] = LDA(lA, mb, ks);
#pragma unroll
        for (int ks = 0; ks < 4; ++ks) Bf[ks] = LDB(lB, 0, ks);
        __builtin_amdgcn_sched_barrier(0);
        if (Hb < NHALF) stage_H(Hb);
        BAR();
        __builtin_amdgcn_s_setprio(1);
#pragma unroll
        for (int ks = 0; ks < 4; ++ks)
#pragma unroll
            for (int mb = 0; mb < 2; ++mb)
                acc[mb][0] = __builtin_amdgcn_mfma_f32_32x32x16_bf16(Af[mb][ks], Bf[ks], acc[mb][0], 0, 0, 0);
        __builtin_amdgcn_s_setprio(0);
        BAR();

        // p1: read A mb2-3 (8); stage (t+2,A0); MFMA Q1
#pragma unroll
        for (int mb = 2; mb < 4; ++mb)
#pragma unroll
            for (int ks = 0; ks < 4; ++ks) Af[mb][ks] = LDA(lA, mb, ks);
        __builtin_amdgcn_sched_barrier(0);
        if (Hb + 1 < NHALF) stage_H(Hb + 1);
        BAR();
        __builtin_amdgcn_s_setprio(1);
#pragma unroll
        for (int ks = 0; ks < 4; ++ks)
#pragma unroll
            for (int mb = 2; mb < 4; ++mb)
                acc[mb][0] = __builtin_amdgcn_mfma_f32_32x32x16_bf16(Af[mb][ks], Bf[ks], acc[mb][0], 0, 0, 0);
        __builtin_amdgcn_s_setprio(0);
        BAR();

        // p2: read B nb1 (4, overwrite Bf); stage (t+2,A1); MFMA Q2
#pragma unroll
        for (int ks = 0; ks < 4; ++ks) Bf[ks] = LDB(lB, 1, ks);
        __builtin_amdgcn_sched_barrier(0);
        if (Hb + 2 < NHALF) stage_H(Hb + 2);
        BAR();
        __builtin_amdgcn_s_setprio(1);
#pragma unroll
        for (int ks = 0; ks < 4; ++ks)
#pragma unroll
            for (int mb = 0; mb < 2; ++mb)
                acc[mb][1] = __builtin_amdgcn_mfma_f32_32x32x16_bf16(Af[mb][ks], Bf[ks], acc[mb][1], 0, 0, 0);
        __builtin_amdgcn_s_setprio(0);
        BAR();

        // p3: no ds_read; stage (t+2,B0); MFMA Q3; counted vmcnt; bar
        if (Hb + 3 < NHALF) stage_H(Hb + 3);
        BAR();
        __builtin_amdgcn_s_setprio(1);
#pragma unroll
        for (int ks = 0; ks < 4; ++ks)
#pragma unroll
            for (int mb = 2; mb < 4; ++mb)
                acc[mb][1] = __builtin_amdgcn_mfma_f32_32x32x16_bf16(Af[mb][ks], Bf[ks], acc[mb][1], 0, 0, 0);
        __builtin_amdgcn_s_setprio(0);
        if (t < NT - 2)       VMCNT(6);   // tile t+1 fully landed, 3 halves in flight
        else if (t == NT - 2) VMCNT(0);   // final drain
        BAR();
    }

    // Epilogue: 32x32 C/D layout col=lane&31, row=(reg&3)+8*(reg>>2)+4*(lane>>5)
    const int ccol = lane & 31;
    const int rhi  = (lane >> 5) * 4;
#pragma unroll
    for (int mb = 0; mb < 4; ++mb)
#pragma unroll
        for (int nb = 0; nb < 2; ++nb) {
            const int col = nBase + wn * 64 + nb * 32 + ccol;
            const int rowB = mBase + wm * 128 + mb * 32 + rhi;
#pragma unroll
            for (int r = 0; r < 16; ++r) {
                const int row = rowB + (r & 3) + 8 * (r >> 2);
                C[(size_t)row * N_DIM + col] = (float)(__bf16)acc[mb][nb][r];
            }
        }
#undef LDA
#undef LDB
}

extern "C" void kernel_launch(void* const* d_in, const int* in_sizes, int n_in,
                              void* d_out, int out_size, void* d_ws, size_t ws_size,
                              hipStream_t stream)
{
    const float* x       = (const float*)d_in[0];
    const int*   qweight = (const int*)d_in[1];
    const float* qscale  = (const float*)d_in[2];
    const int*   qzeros  = (const int*)d_in[3];
    float*       out     = (float*)d_out;

    __bf16* W  = (__bf16*)d_ws;
    __bf16* xb = (__bf16*)((char*)d_ws + (size_t)N_DIM * K_DIM * sizeof(__bf16));

    {
        int total = OUT_F * PACKED;
        dequant_kernel<<<(total + 255) / 256, 256, 0, stream>>>(qweight, qscale, qzeros, W);
    }
    {
        int nch = (M_DIM * K_DIM) / 8;
        cvt_kernel<<<(nch + 255) / 256, 256, 0, stream>>>(x, xb, nch);
    }
    {
        (void)hipFuncSetAttribute((const void*)gemm_kernel,
                                  hipFuncAttributeMaxDynamicSharedMemorySize, 131072);
        dim3 grid((M_DIM / BM) * (N_DIM / BN));   // 512 blocks
        gemm_kernel<<<grid, 512, 131072, stream>>>(xb, W, out);
    }
}